// Round 1
// baseline (2744.426 us; speedup 1.0000x reference)
//
#include <hip/hip_runtime.h>
#include <hip/hip_bf16.h>

#define NN 50000
#define NE 800000
#define DF 256

typedef __attribute__((ext_vector_type(8))) short bf16x8;
typedef __attribute__((ext_vector_type(4))) float f32x4;

__device__ __forceinline__ short f2bf(float f) {
    union { float f; unsigned u; } v; v.f = f;
    unsigned r = (v.u + 0x7fffu + ((v.u >> 16) & 1u)) >> 16;
    return (short)r;
}

// Pack W[k][n] (256x256 f32) into MFMA B-fragment order, bf16:
// P[((nt*8 + kt)*64 + lane)*8 + b] = W[kt*32 + (lane>>4)*8 + b][nt*16 + (lane&15)]
__global__ __launch_bounds__(256) void pack_w_kernel(
    const float* __restrict__ W1, const float* __restrict__ W2,
    short* __restrict__ P1, short* __restrict__ P2) {
    int idx = blockIdx.x * 256 + threadIdx.x;
    if (idx >= 16 * 8 * 64 * 8) return;
    int b    = idx & 7;
    int lane = (idx >> 3) & 63;
    int kt   = (idx >> 9) & 7;
    int nt   = idx >> 12;
    int k = kt * 32 + (lane >> 4) * 8 + b;
    int n = nt * 16 + (lane & 15);
    P1[idx] = f2bf(W1[k * DF + n]);
    P2[idx] = f2bf(W2[k * DF + n]);
}

// One wave per edge: lane covers 4 consecutive floats of the 256-wide row.
__global__ __launch_bounds__(256) void spmm_kernel(
    const float* __restrict__ X, const int* __restrict__ src,
    const int* __restrict__ dst, const float* __restrict__ w,
    float* __restrict__ AX) {
    int e = (blockIdx.x * 256 + threadIdx.x) >> 6;
    int lane = threadIdx.x & 63;
    if (e >= NE) return;
    int s = src[e];
    int d = dst[e];
    float ww = w[e];
    float4 v = *(const float4*)(X + (long)s * DF + lane * 4);
    float* o = AX + (long)d * DF + lane * 4;
    unsafeAtomicAdd(o + 0, v.x * ww);
    unsafeAtomicAdd(o + 1, v.y * ww);
    unsafeAtomicAdd(o + 2, v.z * ww);
    unsafeAtomicAdd(o + 3, v.w * ww);
}

// Fused: agg = ax + x ; nei = ax * x ; out = lrelu(agg@W1 + nei@W2 + b)
// Block = 4 waves; each wave owns 16 rows (full 256-col output).
__global__ __launch_bounds__(256) void fused_gemm_kernel(
    const float* __restrict__ AX, const float* __restrict__ X,
    const short* __restrict__ P1, const short* __restrict__ P2,
    const float* __restrict__ bias, float* __restrict__ out) {
    int wave = threadIdx.x >> 6;
    int lane = threadIdx.x & 63;
    int mbase = blockIdx.x * 64 + wave * 16;
    int arow = mbase + (lane & 15);
    int r = arow < NN ? arow : 0;          // clamp; stores are guarded
    int koff = (lane >> 4) * 8;

    const float* axp = AX + (long)r * DF;
    const float* xp  = X  + (long)r * DF;

    // A-fragments for all 8 k-tiles, both operands, computed once.
    bf16x8 afrag[8], nfrag[8];
    #pragma unroll
    for (int kt = 0; kt < 8; kt++) {
        float a[8], x[8];
        int base = kt * 32 + koff;
        *(float4*)&a[0] = *(const float4*)(axp + base);
        *(float4*)&a[4] = *(const float4*)(axp + base + 4);
        *(float4*)&x[0] = *(const float4*)(xp + base);
        *(float4*)&x[4] = *(const float4*)(xp + base + 4);
        #pragma unroll
        for (int j = 0; j < 8; j++) {
            afrag[kt][j] = f2bf(a[j] + x[j]);   // (A+I)X row fragment
            nfrag[kt][j] = f2bf(a[j] * x[j]);   // (AX)*X row fragment
        }
    }

    const bf16x8* p1 = (const bf16x8*)P1;
    const bf16x8* p2 = (const bf16x8*)P2;
    int col0 = lane & 15;
    int rbase = mbase + (lane >> 4) * 4;

    for (int nt = 0; nt < 16; nt++) {
        f32x4 acc = {0.f, 0.f, 0.f, 0.f};
        #pragma unroll
        for (int kt = 0; kt < 8; kt++) {
            bf16x8 w1 = p1[(nt * 8 + kt) * 64 + lane];
            bf16x8 w2 = p2[(nt * 8 + kt) * 64 + lane];
            acc = __builtin_amdgcn_mfma_f32_16x16x32_bf16(afrag[kt], w1, acc, 0, 0, 0);
            acc = __builtin_amdgcn_mfma_f32_16x16x32_bf16(nfrag[kt], w2, acc, 0, 0, 0);
        }
        int col = nt * 16 + col0;
        float bc = bias[col];
        #pragma unroll
        for (int q = 0; q < 4; q++) {
            int orow = rbase + q;
            if (orow < NN) {
                float v = acc[q] + bc;
                out[(long)orow * DF + col] = v >= 0.f ? v : 0.2f * v;
            }
        }
    }
}

extern "C" void kernel_launch(void* const* d_in, const int* in_sizes, int n_in,
                              void* d_out, int out_size, void* d_ws, size_t ws_size,
                              hipStream_t stream) {
    const float* X  = (const float*)d_in[0];
    const int* src  = (const int*)d_in[1];
    const int* dst  = (const int*)d_in[2];
    const float* w  = (const float*)d_in[3];
    const float* W1 = (const float*)d_in[4];
    const float* W2 = (const float*)d_in[5];
    const float* b  = (const float*)d_in[6];
    float* out = (float*)d_out;

    float* AX = (float*)d_ws;                                    // 50000*256 f32 = 51.2 MB
    short* P1 = (short*)((char*)d_ws + (size_t)NN * DF * 4);     // 64K bf16
    short* P2 = P1 + 16 * 8 * 64 * 8;                            // 64K bf16

    hipMemsetAsync(AX, 0, (size_t)NN * DF * sizeof(float), stream);
    pack_w_kernel<<<(16 * 8 * 64 * 8 + 255) / 256, 256, 0, stream>>>(W1, W2, P1, P2);
    spmm_kernel<<<NE / 4, 256, 0, stream>>>(X, src, dst, w, AX);
    fused_gemm_kernel<<<(NN + 63) / 64, 256, 0, stream>>>(AX, X, P1, P2, b, out);
}

// Round 2
// 360.393 us; speedup vs baseline: 7.6151x; 7.6151x over previous
//
#include <hip/hip_runtime.h>
#include <hip/hip_bf16.h>

#define NN 50000
#define NE 800000
#define DF 256

typedef __attribute__((ext_vector_type(8))) short bf16x8;
typedef __attribute__((ext_vector_type(4))) float f32x4;

__device__ __forceinline__ unsigned short f2bf(float f) {
    union { float f; unsigned u; } v; v.f = f;
    unsigned r = (v.u + 0x7fffu + ((v.u >> 16) & 1u)) >> 16;
    return (unsigned short)r;
}

// Pack W[k][n] (256x256 f32) into MFMA B-fragment order, bf16:
// P[((nt*8 + kt)*64 + lane)*8 + b] = W[kt*32 + (lane>>4)*8 + b][nt*16 + (lane&15)]
__global__ __launch_bounds__(256) void pack_w_kernel(
    const float* __restrict__ W1, const float* __restrict__ W2,
    short* __restrict__ P1, short* __restrict__ P2) {
    int idx = blockIdx.x * 256 + threadIdx.x;
    if (idx >= 16 * 8 * 64 * 8) return;
    int b    = idx & 7;
    int lane = (idx >> 3) & 63;
    int kt   = (idx >> 9) & 7;
    int nt   = idx >> 12;
    int k = kt * 32 + (lane >> 4) * 8 + b;
    int n = nt * 16 + (lane & 15);
    P1[idx] = (short)f2bf(W1[k * DF + n]);
    P2[idx] = (short)f2bf(W2[k * DF + n]);
}

__global__ __launch_bounds__(256) void hist_kernel(
    const int* __restrict__ dst, int* __restrict__ counts) {
    int e = blockIdx.x * 256 + threadIdx.x;
    if (e < NE) atomicAdd(&counts[dst[e]], 1);
}

// Single-block exclusive scan over NN counts -> offsets[NN+1], cursor copy.
__global__ __launch_bounds__(1024) void scan_kernel(
    const int* __restrict__ counts, int* __restrict__ offsets,
    int* __restrict__ cursor) {
    __shared__ int lds[1024];
    __shared__ int carry_s;
    int t = threadIdx.x;
    if (t == 0) carry_s = 0;
    __syncthreads();
    for (int base = 0; base < NN; base += 1024) {
        int i = base + t;
        int v = (i < NN) ? counts[i] : 0;
        lds[t] = v;
        __syncthreads();
        #pragma unroll
        for (int off = 1; off < 1024; off <<= 1) {
            int add = (t >= off) ? lds[t - off] : 0;
            __syncthreads();
            lds[t] += add;
            __syncthreads();
        }
        int incl = lds[t];
        int excl = incl - v + carry_s;
        if (i < NN) { offsets[i] = excl; cursor[i] = excl; }
        __syncthreads();
        if (t == 1023) carry_s += incl;   // chunk total
        __syncthreads();
    }
    if (t == 0) offsets[NN] = carry_s;
}

__global__ __launch_bounds__(256) void scatter_kernel(
    const int* __restrict__ src, const int* __restrict__ dst,
    const float* __restrict__ w, int* __restrict__ cursor,
    int* __restrict__ ssrc, float* __restrict__ sw) {
    int e = blockIdx.x * 256 + threadIdx.x;
    if (e >= NE) return;
    int p = atomicAdd(&cursor[dst[e]], 1);
    ssrc[p] = src[e];
    sw[p]   = w[e];
}

// One wave per dst row: register-accumulate the full 256-wide row,
// then write agg=ax+x and nei=ax*x as bf16 (GEMM A operands).
__global__ __launch_bounds__(256) void gather_kernel(
    const float* __restrict__ X, const int* __restrict__ offsets,
    const int* __restrict__ ssrc, const float* __restrict__ sw,
    short* __restrict__ AGGB, short* __restrict__ NEIB) {
    int wave = threadIdx.x >> 6;
    int lane = threadIdx.x & 63;
    int d = blockIdx.x * 4 + wave;
    if (d >= NN) return;
    int beg = offsets[d];
    int end = offsets[d + 1];
    float4 acc = {0.f, 0.f, 0.f, 0.f};
    for (int j = beg; j < end; ++j) {
        int s = ssrc[j];
        float ww = sw[j];
        float4 v = *(const float4*)(X + (long)s * DF + lane * 4);
        acc.x += v.x * ww; acc.y += v.y * ww;
        acc.z += v.z * ww; acc.w += v.w * ww;
    }
    float4 xv = *(const float4*)(X + (long)d * DF + lane * 4);
    ushort4 ag, ne;
    ag.x = f2bf(acc.x + xv.x); ag.y = f2bf(acc.y + xv.y);
    ag.z = f2bf(acc.z + xv.z); ag.w = f2bf(acc.w + xv.w);
    ne.x = f2bf(acc.x * xv.x); ne.y = f2bf(acc.y * xv.y);
    ne.z = f2bf(acc.z * xv.z); ne.w = f2bf(acc.w * xv.w);
    *(ushort4*)(AGGB + (long)d * DF + lane * 4) = ag;
    *(ushort4*)(NEIB + (long)d * DF + lane * 4) = ne;
}

// out = lrelu(agg@W1 + nei@W2 + b); A operands already bf16-packed rows.
__global__ __launch_bounds__(256) void fused_gemm_kernel(
    const short* __restrict__ AGGB, const short* __restrict__ NEIB,
    const short* __restrict__ P1, const short* __restrict__ P2,
    const float* __restrict__ bias, float* __restrict__ out) {
    int wave = threadIdx.x >> 6;
    int lane = threadIdx.x & 63;
    int mbase = blockIdx.x * 64 + wave * 16;
    int arow = mbase + (lane & 15);
    int r = arow < NN ? arow : 0;          // clamp; stores are guarded
    int koff = (lane >> 4) * 8;

    const short* ap = AGGB + (long)r * DF;
    const short* np = NEIB + (long)r * DF;

    bf16x8 afrag[8], nfrag[8];
    #pragma unroll
    for (int kt = 0; kt < 8; kt++) {
        afrag[kt] = *(const bf16x8*)(ap + kt * 32 + koff);
        nfrag[kt] = *(const bf16x8*)(np + kt * 32 + koff);
    }

    const bf16x8* p1 = (const bf16x8*)P1;
    const bf16x8* p2 = (const bf16x8*)P2;
    int col0 = lane & 15;
    int rbase = mbase + (lane >> 4) * 4;

    for (int nt = 0; nt < 16; nt++) {
        f32x4 acc = {0.f, 0.f, 0.f, 0.f};
        #pragma unroll
        for (int kt = 0; kt < 8; kt++) {
            bf16x8 w1 = p1[(nt * 8 + kt) * 64 + lane];
            bf16x8 w2 = p2[(nt * 8 + kt) * 64 + lane];
            acc = __builtin_amdgcn_mfma_f32_16x16x32_bf16(afrag[kt], w1, acc, 0, 0, 0);
            acc = __builtin_amdgcn_mfma_f32_16x16x32_bf16(nfrag[kt], w2, acc, 0, 0, 0);
        }
        int col = nt * 16 + col0;
        float bc = bias[col];
        #pragma unroll
        for (int q = 0; q < 4; q++) {
            int orow = rbase + q;
            if (orow < NN) {
                float v = acc[q] + bc;
                out[(long)orow * DF + col] = v >= 0.f ? v : 0.2f * v;
            }
        }
    }
}

extern "C" void kernel_launch(void* const* d_in, const int* in_sizes, int n_in,
                              void* d_out, int out_size, void* d_ws, size_t ws_size,
                              hipStream_t stream) {
    const float* X  = (const float*)d_in[0];
    const int* src  = (const int*)d_in[1];
    const int* dst  = (const int*)d_in[2];
    const float* w  = (const float*)d_in[3];
    const float* W1 = (const float*)d_in[4];
    const float* W2 = (const float*)d_in[5];
    const float* b  = (const float*)d_in[6];
    float* out = (float*)d_out;

    char* ws = (char*)d_ws;
    size_t off = 0;
    auto alloc = [&](size_t bytes) {
        char* p = ws + off;
        off = (off + bytes + 255) & ~(size_t)255;
        return p;
    };
    short* AGGB   = (short*)alloc((size_t)NN * DF * 2);   // 25.6 MB
    short* NEIB   = (short*)alloc((size_t)NN * DF * 2);   // 25.6 MB
    short* P1     = (short*)alloc(16 * 8 * 64 * 8 * 2);   // 128 KB
    short* P2     = (short*)alloc(16 * 8 * 64 * 8 * 2);   // 128 KB
    int*   counts = (int*)alloc((size_t)NN * 4);
    int*   offs   = (int*)alloc((size_t)(NN + 1) * 4);
    int*   cursor = (int*)alloc((size_t)NN * 4);
    int*   ssrc   = (int*)alloc((size_t)NE * 4);          // 3.2 MB
    float* sw     = (float*)alloc((size_t)NE * 4);        // 3.2 MB

    hipMemsetAsync(counts, 0, (size_t)NN * 4, stream);
    pack_w_kernel<<<(16 * 8 * 64 * 8 + 255) / 256, 256, 0, stream>>>(W1, W2, P1, P2);
    hist_kernel<<<(NE + 255) / 256, 256, 0, stream>>>(dst, counts);
    scan_kernel<<<1, 1024, 0, stream>>>(counts, offs, cursor);
    scatter_kernel<<<(NE + 255) / 256, 256, 0, stream>>>(src, dst, w, cursor, ssrc, sw);
    gather_kernel<<<(NN + 3) / 4, 256, 0, stream>>>(X, offs, ssrc, sw, AGGB, NEIB);
    fused_gemm_kernel<<<(NN + 63) / 64, 256, 0, stream>>>(AGGB, NEIB, P1, P2, b, out);
}

// Round 3
// 226.106 us; speedup vs baseline: 12.1378x; 1.5939x over previous
//
#include <hip/hip_runtime.h>
#include <hip/hip_bf16.h>

#define NN 50000
#define NE 800000
#define DF 256
#define NBLK 49           // ceil(NN/1024)
#define CONV_BLOCKS 12500 // 12.8M elems / 1024
#define HIST_BLOCKS 3125  // NE / 256
#define PACK_BLOCKS 256   // 65536 / 256

typedef __attribute__((ext_vector_type(8))) short bf16x8;
typedef __attribute__((ext_vector_type(4))) float f32x4;

__device__ __forceinline__ unsigned short f2bf(float f) {
    union { float f; unsigned u; } v; v.f = f;
    unsigned r = (v.u + 0x7fffu + ((v.u >> 16) & 1u)) >> 16;
    return (unsigned short)r;
}
__device__ __forceinline__ float bf2f(unsigned short u) {
    union { unsigned u; float f; } v; v.u = ((unsigned)u) << 16;
    return v.f;
}

// Fused prep: X->bf16 copy | histogram of dst | pack W1/W2 to MFMA B-frag order.
__global__ __launch_bounds__(256) void prep_kernel(
    const float* __restrict__ X, const int* __restrict__ dst,
    const float* __restrict__ W1, const float* __restrict__ W2,
    unsigned short* __restrict__ XB, int* __restrict__ counts,
    short* __restrict__ P1, short* __restrict__ P2) {
    int b = blockIdx.x;
    if (b < CONV_BLOCKS) {
        int i = b * 1024 + threadIdx.x * 4;          // 12500*1024 = 12.8M exact
        float4 v = *(const float4*)(X + i);
        ushort4 o;
        o.x = f2bf(v.x); o.y = f2bf(v.y); o.z = f2bf(v.z); o.w = f2bf(v.w);
        *(ushort4*)(XB + i) = o;
    } else if (b < CONV_BLOCKS + HIST_BLOCKS) {
        int e = (b - CONV_BLOCKS) * 256 + threadIdx.x;   // 3125*256 = 800000 exact
        atomicAdd(&counts[dst[e]], 1);
    } else {
        int idx = (b - CONV_BLOCKS - HIST_BLOCKS) * 256 + threadIdx.x; // < 65536
        int bb   = idx & 7;
        int lane = (idx >> 3) & 63;
        int kt   = (idx >> 9) & 7;
        int nt   = idx >> 12;
        int k = kt * 32 + (lane >> 4) * 8 + bb;
        int n = nt * 16 + (lane & 15);
        P1[idx] = (short)f2bf(W1[k * DF + n]);
        P2[idx] = (short)f2bf(W2[k * DF + n]);
    }
}

// Hierarchical scan, stage 1: per-block (1024 counts) exclusive scan + block sum.
__global__ __launch_bounds__(256) void scan1_kernel(
    const int* __restrict__ counts, int* __restrict__ offsets,
    int* __restrict__ bsums) {
    __shared__ int wsum[4];
    int t = threadIdx.x;
    int lane = t & 63, wv = t >> 6;
    int base = blockIdx.x * 1024 + t * 4;
    int4 c = {0, 0, 0, 0};
    if (base + 3 < NN) c = *(const int4*)(counts + base);
    else {
        if (base + 0 < NN) c.x = counts[base + 0];
        if (base + 1 < NN) c.y = counts[base + 1];
        if (base + 2 < NN) c.z = counts[base + 2];
        if (base + 3 < NN) c.w = counts[base + 3];
    }
    int s = c.x + c.y + c.z + c.w;
    int x = s;
    #pragma unroll
    for (int off = 1; off < 64; off <<= 1) {
        int y = __shfl_up(x, off);
        if (lane >= off) x += y;
    }
    if (lane == 63) wsum[wv] = x;
    __syncthreads();
    int woff = 0;
    for (int i = 0; i < wv; i++) woff += wsum[i];
    int e0 = woff + x - s;
    int4 o; o.x = e0; o.y = o.x + c.x; o.z = o.y + c.y; o.w = o.z + c.z;
    if (base + 3 < NN) *(int4*)(offsets + base) = o;
    else {
        if (base + 0 < NN) offsets[base + 0] = o.x;
        if (base + 1 < NN) offsets[base + 1] = o.y;
        if (base + 2 < NN) offsets[base + 2] = o.z;
        if (base + 3 < NN) offsets[base + 3] = o.w;
    }
    if (t == 255) bsums[blockIdx.x] = woff + x;
}

// Stage 2: one wave scans the 49 block sums; writes offsets[NN]=total.
__global__ __launch_bounds__(64) void scan2_kernel(
    const int* __restrict__ bsums, int* __restrict__ boffs,
    int* __restrict__ offsets) {
    int t = threadIdx.x;
    int v = (t < NBLK) ? bsums[t] : 0;
    int x = v;
    #pragma unroll
    for (int off = 1; off < 64; off <<= 1) {
        int y = __shfl_up(x, off);
        if (t >= off) x += y;
    }
    if (t < NBLK) boffs[t] = x - v;
    if (t == 63) offsets[NN] = x;
}

// Stage 3: add block offsets; produce cursor copy.
__global__ __launch_bounds__(256) void scan3_kernel(
    int* __restrict__ offsets, int* __restrict__ cursor,
    const int* __restrict__ boffs) {
    int base = blockIdx.x * 1024 + threadIdx.x * 4;
    int bo = boffs[blockIdx.x];
    if (base + 3 < NN) {
        int4 o = *(const int4*)(offsets + base);
        o.x += bo; o.y += bo; o.z += bo; o.w += bo;
        *(int4*)(offsets + base) = o;
        *(int4*)(cursor + base) = o;
    } else {
        for (int k = 0; k < 4; k++)
            if (base + k < NN) {
                int vv = offsets[base + k] + bo;
                offsets[base + k] = vv;
                cursor[base + k] = vv;
            }
    }
}

// Bucket edges by dst: one (src, w_bits) record per edge.
__global__ __launch_bounds__(256) void scatter_kernel(
    const int* __restrict__ src, const int* __restrict__ dst,
    const float* __restrict__ w, int* __restrict__ cursor,
    int2* __restrict__ edges) {
    int e = blockIdx.x * 256 + threadIdx.x;
    if (e >= NE) return;
    int p = atomicAdd(&cursor[dst[e]], 1);
    edges[p] = make_int2(src[e], __float_as_int(w[e]));
}

// One wave per dst row: f32-accumulate bf16 gathered rows, write agg/nei bf16.
__global__ __launch_bounds__(256) void gather_kernel(
    const unsigned short* __restrict__ XB, const float* __restrict__ X,
    const int* __restrict__ offsets, const int2* __restrict__ edges,
    short* __restrict__ AGGB, short* __restrict__ NEIB) {
    int wave = threadIdx.x >> 6;
    int lane = threadIdx.x & 63;
    int d = blockIdx.x * 4 + wave;
    if (d >= NN) return;
    int beg = offsets[d];
    int end = offsets[d + 1];
    float a0 = 0.f, a1 = 0.f, a2 = 0.f, a3 = 0.f;
    int j = beg;
    for (; j + 1 < end; j += 2) {
        int2 r0 = edges[j];
        int2 r1 = edges[j + 1];
        float w0 = __int_as_float(r0.y);
        float w1 = __int_as_float(r1.y);
        ushort4 u0 = *(const ushort4*)(XB + (long)r0.x * DF + lane * 4);
        ushort4 u1 = *(const ushort4*)(XB + (long)r1.x * DF + lane * 4);
        a0 += bf2f(u0.x) * w0; a1 += bf2f(u0.y) * w0;
        a2 += bf2f(u0.z) * w0; a3 += bf2f(u0.w) * w0;
        a0 += bf2f(u1.x) * w1; a1 += bf2f(u1.y) * w1;
        a2 += bf2f(u1.z) * w1; a3 += bf2f(u1.w) * w1;
    }
    if (j < end) {
        int2 r0 = edges[j];
        float w0 = __int_as_float(r0.y);
        ushort4 u0 = *(const ushort4*)(XB + (long)r0.x * DF + lane * 4);
        a0 += bf2f(u0.x) * w0; a1 += bf2f(u0.y) * w0;
        a2 += bf2f(u0.z) * w0; a3 += bf2f(u0.w) * w0;
    }
    float4 xv = *(const float4*)(X + (long)d * DF + lane * 4);
    ushort4 ag, ne;
    ag.x = f2bf(a0 + xv.x); ag.y = f2bf(a1 + xv.y);
    ag.z = f2bf(a2 + xv.z); ag.w = f2bf(a3 + xv.w);
    ne.x = f2bf(a0 * xv.x); ne.y = f2bf(a1 * xv.y);
    ne.z = f2bf(a2 * xv.z); ne.w = f2bf(a3 * xv.w);
    *(ushort4*)(AGGB + (long)d * DF + lane * 4) = ag;
    *(ushort4*)(NEIB + (long)d * DF + lane * 4) = ne;
}

// out = lrelu(agg@W1 + nei@W2 + b); A operands already bf16-packed rows.
__global__ __launch_bounds__(256) void fused_gemm_kernel(
    const short* __restrict__ AGGB, const short* __restrict__ NEIB,
    const short* __restrict__ P1, const short* __restrict__ P2,
    const float* __restrict__ bias, float* __restrict__ out) {
    int wave = threadIdx.x >> 6;
    int lane = threadIdx.x & 63;
    int mbase = blockIdx.x * 64 + wave * 16;
    int arow = mbase + (lane & 15);
    int r = arow < NN ? arow : 0;          // clamp; stores are guarded
    int koff = (lane >> 4) * 8;

    const short* ap = AGGB + (long)r * DF;
    const short* np = NEIB + (long)r * DF;

    bf16x8 afrag[8], nfrag[8];
    #pragma unroll
    for (int kt = 0; kt < 8; kt++) {
        afrag[kt] = *(const bf16x8*)(ap + kt * 32 + koff);
        nfrag[kt] = *(const bf16x8*)(np + kt * 32 + koff);
    }

    const bf16x8* p1 = (const bf16x8*)P1;
    const bf16x8* p2 = (const bf16x8*)P2;
    int col0 = lane & 15;
    int rbase = mbase + (lane >> 4) * 4;

    for (int nt = 0; nt < 16; nt++) {
        f32x4 acc = {0.f, 0.f, 0.f, 0.f};
        #pragma unroll
        for (int kt = 0; kt < 8; kt++) {
            bf16x8 w1 = p1[(nt * 8 + kt) * 64 + lane];
            bf16x8 w2 = p2[(nt * 8 + kt) * 64 + lane];
            acc = __builtin_amdgcn_mfma_f32_16x16x32_bf16(afrag[kt], w1, acc, 0, 0, 0);
            acc = __builtin_amdgcn_mfma_f32_16x16x32_bf16(nfrag[kt], w2, acc, 0, 0, 0);
        }
        int col = nt * 16 + col0;
        float bc = bias[col];
        #pragma unroll
        for (int q = 0; q < 4; q++) {
            int orow = rbase + q;
            if (orow < NN) {
                float v = acc[q] + bc;
                out[(long)orow * DF + col] = v >= 0.f ? v : 0.2f * v;
            }
        }
    }
}

extern "C" void kernel_launch(void* const* d_in, const int* in_sizes, int n_in,
                              void* d_out, int out_size, void* d_ws, size_t ws_size,
                              hipStream_t stream) {
    const float* X  = (const float*)d_in[0];
    const int* src  = (const int*)d_in[1];
    const int* dst  = (const int*)d_in[2];
    const float* w  = (const float*)d_in[3];
    const float* W1 = (const float*)d_in[4];
    const float* W2 = (const float*)d_in[5];
    const float* b  = (const float*)d_in[6];
    float* out = (float*)d_out;

    char* ws = (char*)d_ws;
    size_t off = 0;
    auto alloc = [&](size_t bytes) {
        char* p = ws + off;
        off = (off + bytes + 255) & ~(size_t)255;
        return p;
    };
    short* AGGB            = (short*)alloc((size_t)NN * DF * 2);          // 25.6 MB
    short* NEIB            = (short*)alloc((size_t)NN * DF * 2);          // 25.6 MB
    unsigned short* XB     = (unsigned short*)alloc((size_t)NN * DF * 2); // 25.6 MB
    short* P1              = (short*)alloc(16 * 8 * 64 * 8 * 2);          // 128 KB
    short* P2              = (short*)alloc(16 * 8 * 64 * 8 * 2);          // 128 KB
    int*   counts          = (int*)alloc((size_t)NN * 4);
    int*   offs            = (int*)alloc((size_t)(NN + 1) * 4);
    int*   cursor          = (int*)alloc((size_t)NN * 4);
    int*   bsums           = (int*)alloc(NBLK * 4);
    int*   boffs           = (int*)alloc(NBLK * 4);
    int2*  edges           = (int2*)alloc((size_t)NE * 8);                // 6.4 MB

    hipMemsetAsync(counts, 0, (size_t)NN * 4, stream);
    prep_kernel<<<CONV_BLOCKS + HIST_BLOCKS + PACK_BLOCKS, 256, 0, stream>>>(
        X, dst, W1, W2, XB, counts, P1, P2);
    scan1_kernel<<<NBLK, 256, 0, stream>>>(counts, offs, bsums);
    scan2_kernel<<<1, 64, 0, stream>>>(bsums, boffs, offs);
    scan3_kernel<<<NBLK, 256, 0, stream>>>(offs, cursor, boffs);
    scatter_kernel<<<(NE + 255) / 256, 256, 0, stream>>>(src, dst, w, cursor, edges);
    gather_kernel<<<(NN + 3) / 4, 256, 0, stream>>>(XB, X, offs, edges, AGGB, NEIB);
    fused_gemm_kernel<<<(NN + 63) / 64, 256, 0, stream>>>(AGGB, NEIB, P1, P2, b, out);
}

// Round 4
// 192.136 us; speedup vs baseline: 14.2838x; 1.1768x over previous
//
#include <hip/hip_runtime.h>
#include <hip/hip_bf16.h>

#define NN 50000
#define NE 800000
#define DF 256
#define NBLK 49           // ceil(NN/1024)
#define CONV_BLOCKS 12500 // 12.8M elems / 1024
#define HIST_BLOCKS 3125  // NE / 256
#define PACK_BLOCKS 256   // 65536 / 256

typedef __attribute__((ext_vector_type(8))) short bf16x8;
typedef __attribute__((ext_vector_type(4))) float f32x4;

__device__ __forceinline__ unsigned short f2bf(float f) {
    union { float f; unsigned u; } v; v.f = f;
    unsigned r = (v.u + 0x7fffu + ((v.u >> 16) & 1u)) >> 16;
    return (unsigned short)r;
}
__device__ __forceinline__ float bf2f(unsigned short u) {
    union { unsigned u; float f; } v; v.u = ((unsigned)u) << 16;
    return v.f;
}

// Fused prep: X->bf16 copy | histogram of dst | pack W1/W2 to MFMA B-frag order.
__global__ __launch_bounds__(256) void prep_kernel(
    const float* __restrict__ X, const int* __restrict__ dst,
    const float* __restrict__ W1, const float* __restrict__ W2,
    unsigned short* __restrict__ XB, int* __restrict__ counts,
    short* __restrict__ P1, short* __restrict__ P2) {
    int b = blockIdx.x;
    if (b < CONV_BLOCKS) {
        int i = b * 1024 + threadIdx.x * 4;          // 12500*1024 = 12.8M exact
        float4 v = *(const float4*)(X + i);
        ushort4 o;
        o.x = f2bf(v.x); o.y = f2bf(v.y); o.z = f2bf(v.z); o.w = f2bf(v.w);
        *(ushort4*)(XB + i) = o;
    } else if (b < CONV_BLOCKS + HIST_BLOCKS) {
        int e = (b - CONV_BLOCKS) * 256 + threadIdx.x;   // 3125*256 = 800000 exact
        atomicAdd(&counts[dst[e]], 1);
    } else {
        int idx = (b - CONV_BLOCKS - HIST_BLOCKS) * 256 + threadIdx.x; // < 65536
        int bb   = idx & 7;
        int lane = (idx >> 3) & 63;
        int kt   = (idx >> 9) & 7;
        int nt   = idx >> 12;
        int k = kt * 32 + (lane >> 4) * 8 + bb;
        int n = nt * 16 + (lane & 15);
        P1[idx] = (short)f2bf(W1[k * DF + n]);
        P2[idx] = (short)f2bf(W2[k * DF + n]);
    }
}

// Hierarchical scan, stage 1: per-block (1024 counts) exclusive scan + block sum.
__global__ __launch_bounds__(256) void scan1_kernel(
    const int* __restrict__ counts, int* __restrict__ offsets,
    int* __restrict__ bsums) {
    __shared__ int wsum[4];
    int t = threadIdx.x;
    int lane = t & 63, wv = t >> 6;
    int base = blockIdx.x * 1024 + t * 4;
    int4 c = {0, 0, 0, 0};
    if (base + 3 < NN) c = *(const int4*)(counts + base);
    else {
        if (base + 0 < NN) c.x = counts[base + 0];
        if (base + 1 < NN) c.y = counts[base + 1];
        if (base + 2 < NN) c.z = counts[base + 2];
        if (base + 3 < NN) c.w = counts[base + 3];
    }
    int s = c.x + c.y + c.z + c.w;
    int x = s;
    #pragma unroll
    for (int off = 1; off < 64; off <<= 1) {
        int y = __shfl_up(x, off);
        if (lane >= off) x += y;
    }
    if (lane == 63) wsum[wv] = x;
    __syncthreads();
    int woff = 0;
    for (int i = 0; i < wv; i++) woff += wsum[i];
    int e0 = woff + x - s;
    int4 o; o.x = e0; o.y = o.x + c.x; o.z = o.y + c.y; o.w = o.z + c.z;
    if (base + 3 < NN) *(int4*)(offsets + base) = o;
    else {
        if (base + 0 < NN) offsets[base + 0] = o.x;
        if (base + 1 < NN) offsets[base + 1] = o.y;
        if (base + 2 < NN) offsets[base + 2] = o.z;
        if (base + 3 < NN) offsets[base + 3] = o.w;
    }
    if (t == 255) bsums[blockIdx.x] = woff + x;
}

// Stage 2+3 fused: every block re-scans the 49 block sums in one wave,
// adds its block offset, writes final offsets + cursor copy.
__global__ __launch_bounds__(256) void scan23_kernel(
    int* __restrict__ offsets, int* __restrict__ cursor,
    const int* __restrict__ bsums) {
    __shared__ int bo_s;
    int t = threadIdx.x;
    if (t < 64) {
        int v = (t < NBLK) ? bsums[t] : 0;
        int x = v;
        #pragma unroll
        for (int off = 1; off < 64; off <<= 1) {
            int y = __shfl_up(x, off);
            if (t >= off) x += y;
        }
        if (t == (int)blockIdx.x) bo_s = x - v;              // exclusive at bid
        if (blockIdx.x == NBLK - 1 && t == NBLK - 1) offsets[NN] = x;
    }
    __syncthreads();
    int bo = bo_s;
    int base = blockIdx.x * 1024 + t * 4;
    if (base + 3 < NN) {
        int4 o = *(const int4*)(offsets + base);
        o.x += bo; o.y += bo; o.z += bo; o.w += bo;
        *(int4*)(offsets + base) = o;
        *(int4*)(cursor + base) = o;
    } else {
        for (int k = 0; k < 4; k++)
            if (base + k < NN) {
                int vv = offsets[base + k] + bo;
                offsets[base + k] = vv;
                cursor[base + k] = vv;
            }
    }
}

// Bucket edges by dst: one (src, w_bits) record per edge.
__global__ __launch_bounds__(256) void scatter_kernel(
    const int* __restrict__ src, const int* __restrict__ dst,
    const float* __restrict__ w, int* __restrict__ cursor,
    int2* __restrict__ edges) {
    int e = blockIdx.x * 256 + threadIdx.x;
    if (e >= NE) return;
    int p = atomicAdd(&cursor[dst[e]], 1);
    edges[p] = make_int2(src[e], __float_as_int(w[e]));
}

// Fused gather + GEMM. Block = 16 dst rows (4 waves).
// Phase 1: wave gathers 4 rows, writes agg/nei bf16 rows to LDS (XOR-swizzled).
// Phase 2: each wave does 4 of 16 col-tiles: out = lrelu(agg@W1 + nei@W2 + b).
__global__ __launch_bounds__(256, 4) void gather_gemm_kernel(
    const unsigned short* __restrict__ XB, const int* __restrict__ offsets,
    const int2* __restrict__ edges, const short* __restrict__ P1,
    const short* __restrict__ P2, const float* __restrict__ bias,
    float* __restrict__ out) {
    __shared__ short AGG[16 * DF];
    __shared__ short NEI[16 * DF];
    int wave = threadIdx.x >> 6;
    int lane = threadIdx.x & 63;
    int d0 = blockIdx.x * 16;      // NN = 16*3125 exact, no guards needed

    #pragma unroll
    for (int rr = 0; rr < 4; rr++) {
        int row = wave * 4 + rr;
        int d = d0 + row;
        int beg = offsets[d];
        int end = offsets[d + 1];
        float a0 = 0.f, a1 = 0.f, a2 = 0.f, a3 = 0.f;
        int j = beg;
        for (; j + 3 < end; j += 4) {
            int2 r0 = edges[j + 0];
            int2 r1 = edges[j + 1];
            int2 r2 = edges[j + 2];
            int2 r3 = edges[j + 3];
            ushort4 u0 = *(const ushort4*)(XB + (long)r0.x * DF + lane * 4);
            ushort4 u1 = *(const ushort4*)(XB + (long)r1.x * DF + lane * 4);
            ushort4 u2 = *(const ushort4*)(XB + (long)r2.x * DF + lane * 4);
            ushort4 u3 = *(const ushort4*)(XB + (long)r3.x * DF + lane * 4);
            float w0 = __int_as_float(r0.y), w1 = __int_as_float(r1.y);
            float w2 = __int_as_float(r2.y), w3 = __int_as_float(r3.y);
            a0 += bf2f(u0.x) * w0; a1 += bf2f(u0.y) * w0;
            a2 += bf2f(u0.z) * w0; a3 += bf2f(u0.w) * w0;
            a0 += bf2f(u1.x) * w1; a1 += bf2f(u1.y) * w1;
            a2 += bf2f(u1.z) * w1; a3 += bf2f(u1.w) * w1;
            a0 += bf2f(u2.x) * w2; a1 += bf2f(u2.y) * w2;
            a2 += bf2f(u2.z) * w2; a3 += bf2f(u2.w) * w2;
            a0 += bf2f(u3.x) * w3; a1 += bf2f(u3.y) * w3;
            a2 += bf2f(u3.z) * w3; a3 += bf2f(u3.w) * w3;
        }
        for (; j < end; ++j) {
            int2 r0 = edges[j];
            float w0 = __int_as_float(r0.y);
            ushort4 u0 = *(const ushort4*)(XB + (long)r0.x * DF + lane * 4);
            a0 += bf2f(u0.x) * w0; a1 += bf2f(u0.y) * w0;
            a2 += bf2f(u0.z) * w0; a3 += bf2f(u0.w) * w0;
        }
        ushort4 xu = *(const ushort4*)(XB + (long)d * DF + lane * 4);
        float x0 = bf2f(xu.x), x1 = bf2f(xu.y), x2 = bf2f(xu.z), x3 = bf2f(xu.w);
        ushort4 ag, ne;
        ag.x = f2bf(a0 + x0); ag.y = f2bf(a1 + x1);
        ag.z = f2bf(a2 + x2); ag.w = f2bf(a3 + x3);
        ne.x = f2bf(a0 * x0); ne.y = f2bf(a1 * x1);
        ne.z = f2bf(a2 * x2); ne.w = f2bf(a3 * x3);
        // XOR-swizzled LDS store: 16B chunk c of row r lands at slot c^(r&7).
        int sidx = row * DF + (((lane >> 1) ^ (row & 7)) << 3) + ((lane & 1) << 2);
        *(ushort4*)&AGG[sidx] = ag;
        *(ushort4*)&NEI[sidx] = ne;
    }
    __syncthreads();

    int arow = lane & 15;
    int hi = lane >> 4;
    bf16x8 afrag[8], nfrag[8];
    #pragma unroll
    for (int kt = 0; kt < 8; kt++) {
        int sc = (kt * 4 + hi) ^ (arow & 7);
        afrag[kt] = *(const bf16x8*)&AGG[arow * DF + sc * 8];
        nfrag[kt] = *(const bf16x8*)&NEI[arow * DF + sc * 8];
    }

    const bf16x8* p1 = (const bf16x8*)P1;
    const bf16x8* p2 = (const bf16x8*)P2;
    #pragma unroll
    for (int ntl = 0; ntl < 4; ntl++) {
        int nt = wave * 4 + ntl;
        f32x4 acc = {0.f, 0.f, 0.f, 0.f};
        #pragma unroll
        for (int kt = 0; kt < 8; kt++) {
            acc = __builtin_amdgcn_mfma_f32_16x16x32_bf16(afrag[kt], p1[(nt * 8 + kt) * 64 + lane], acc, 0, 0, 0);
            acc = __builtin_amdgcn_mfma_f32_16x16x32_bf16(nfrag[kt], p2[(nt * 8 + kt) * 64 + lane], acc, 0, 0, 0);
        }
        int col = nt * 16 + (lane & 15);
        float bc = bias[col];
        #pragma unroll
        for (int q = 0; q < 4; q++) {
            int orow = d0 + hi * 4 + q;
            float v = acc[q] + bc;
            out[(long)orow * DF + col] = v >= 0.f ? v : 0.2f * v;
        }
    }
}

extern "C" void kernel_launch(void* const* d_in, const int* in_sizes, int n_in,
                              void* d_out, int out_size, void* d_ws, size_t ws_size,
                              hipStream_t stream) {
    const float* X  = (const float*)d_in[0];
    const int* src  = (const int*)d_in[1];
    const int* dst  = (const int*)d_in[2];
    const float* w  = (const float*)d_in[3];
    const float* W1 = (const float*)d_in[4];
    const float* W2 = (const float*)d_in[5];
    const float* b  = (const float*)d_in[6];
    float* out = (float*)d_out;

    char* ws = (char*)d_ws;
    size_t off = 0;
    auto alloc = [&](size_t bytes) {
        char* p = ws + off;
        off = (off + bytes + 255) & ~(size_t)255;
        return p;
    };
    unsigned short* XB = (unsigned short*)alloc((size_t)NN * DF * 2); // 25.6 MB
    short* P1          = (short*)alloc(16 * 8 * 64 * 8 * 2);          // 128 KB
    short* P2          = (short*)alloc(16 * 8 * 64 * 8 * 2);          // 128 KB
    int*   counts      = (int*)alloc((size_t)NN * 4);
    int*   offs        = (int*)alloc((size_t)(NN + 1) * 4);
    int*   cursor      = (int*)alloc((size_t)NN * 4);
    int*   bsums       = (int*)alloc(NBLK * 4);
    int2*  edges       = (int2*)alloc((size_t)NE * 8);                // 6.4 MB

    hipMemsetAsync(counts, 0, (size_t)NN * 4, stream);
    prep_kernel<<<CONV_BLOCKS + HIST_BLOCKS + PACK_BLOCKS, 256, 0, stream>>>(
        X, dst, W1, W2, XB, counts, P1, P2);
    scan1_kernel<<<NBLK, 256, 0, stream>>>(counts, offs, bsums);
    scan23_kernel<<<NBLK, 256, 0, stream>>>(offs, cursor, bsums);
    scatter_kernel<<<(NE + 255) / 256, 256, 0, stream>>>(src, dst, w, cursor, edges);
    gather_gemm_kernel<<<NN / 16, 256, 0, stream>>>(XB, offs, edges, P1, P2, b, out);
}